// Round 2
// baseline (3767.696 us; speedup 1.0000x reference)
//
#include <hip/hip_runtime.h>

#define NT_TOK 32768
#define DM 1024
#define DH 4096
#define NE 8
#define BM 128
#define BN 128
#define BKK 64
#define CAP (NT_TOK*2 + NE*BM)   /* 66560 padded assignment capacity */

typedef _Float16 f16x8 __attribute__((ext_vector_type(8)));
typedef float f32x4 __attribute__((ext_vector_type(4)));
typedef float f32x8 __attribute__((ext_vector_type(8)));

__device__ __forceinline__ unsigned short f2h_bits(float v){
  _Float16 h = (_Float16)v;
  return __builtin_bit_cast(unsigned short, h);
}

__device__ __forceinline__ void async16(const void* g, void* l){
  __builtin_amdgcn_global_load_lds((const __attribute__((address_space(1))) void*)g,
                                   (__attribute__((address_space(3))) void*)l, 16, 0, 0);
}

// ---------------- prep kernels ----------------

__global__ __launch_bounds__(256) void cvt_f16_kernel(const float* __restrict__ src,
                                                      unsigned short* __restrict__ dst, int n8){
  int i = blockIdx.x*256 + threadIdx.x;
  if (i >= n8) return;
  float4 a = ((const float4*)src)[2*i];
  float4 b = ((const float4*)src)[2*i+1];
  union { unsigned short u[8]; uint4 v; } r;
  r.u[0]=f2h_bits(a.x); r.u[1]=f2h_bits(a.y); r.u[2]=f2h_bits(a.z); r.u[3]=f2h_bits(a.w);
  r.u[4]=f2h_bits(b.x); r.u[5]=f2h_bits(b.y); r.u[6]=f2h_bits(b.z); r.u[7]=f2h_bits(b.w);
  ((uint4*)dst)[i] = r.v;
}

// src [E][R][C] f32 -> dst [E][C][R] f16
__global__ void transpose_f16_kernel(const float* __restrict__ src,
                                     unsigned short* __restrict__ dst, int R, int C){
  __shared__ float t[32][33];
  int ez = blockIdx.z;
  const float* s = src + (size_t)ez*R*C;
  unsigned short* d = dst + (size_t)ez*R*C;
  int c0 = blockIdx.x*32, r0 = blockIdx.y*32;
  int tx = threadIdx.x, ty = threadIdx.y;
  #pragma unroll
  for (int i=0;i<32;i+=8)
    t[ty+i][tx] = s[(size_t)(r0+ty+i)*C + (c0+tx)];
  __syncthreads();
  #pragma unroll
  for (int i=0;i<32;i+=8)
    d[(size_t)(c0+ty+i)*R + (r0+tx)] = f2h_bits(t[tx][ty+i]);
}

// ---------------- router (f64 accumulate -> top-2 selection matches np ref) ----------------

__global__ __launch_bounds__(256) void router_kernel(const float* __restrict__ x,
    const float* __restrict__ Wr, const float* __restrict__ br,
    int* __restrict__ topi, float* __restrict__ topw, int* __restrict__ counts){
  __shared__ float wr_s[NE*DM];
  int tid = threadIdx.x;
  for (int idx=tid; idx<NE*DM; idx+=256){
    int k = idx>>3, e = idx&7;
    wr_s[e*DM + k] = Wr[idx];
  }
  __syncthreads();
  int w = tid>>6, lane = tid&63;
  int t = blockIdx.x*4 + w;
  const float* xr = x + (size_t)t*DM;
  double acc[NE];
  #pragma unroll
  for (int e=0;e<NE;e++) acc[e]=0.0;
  for (int j=0;j<16;j++){
    float xv = xr[j*64 + lane];
    #pragma unroll
    for (int e=0;e<NE;e++) acc[e] += (double)xv * (double)wr_s[e*DM + j*64 + lane];
  }
  #pragma unroll
  for (int e=0;e<NE;e++){
    #pragma unroll
    for (int d=32; d; d>>=1) acc[e] += __shfl_xor(acc[e], d);
  }
  if (lane==0){
    double l[NE];
    #pragma unroll
    for (int e=0;e<NE;e++) l[e] = acc[e] + (double)br[e];
    int i0 = 0;
    #pragma unroll
    for (int e=1;e<NE;e++) if (l[e] > l[i0]) i0 = e;
    int i1 = (i0==0) ? 1 : 0;
    #pragma unroll
    for (int e=0;e<NE;e++) if (e != i0 && l[e] > l[i1]) i1 = e;
    double w0 = 1.0/(1.0 + exp(l[i1]-l[i0]));   // renormalized top-2 softmax, exact identity
    topi[2*t] = i0; topi[2*t+1] = i1;
    topw[2*t] = (float)w0; topw[2*t+1] = (float)(1.0-w0);
    atomicAdd(&counts[i0],1); atomicAdd(&counts[i1],1);
  }
}

__global__ void offsets_kernel(const int* __restrict__ counts, int* __restrict__ off){
  if (threadIdx.x==0 && blockIdx.x==0){
    int o = 0;
    for (int e=0;e<NE;e++){ off[e] = o; o += ((counts[e]+BM-1)/BM)*BM; }
    off[NE] = o;
  }
}

__global__ __launch_bounds__(256) void scatter_kernel(const int* __restrict__ topi,
    const float* __restrict__ topw, const int* __restrict__ off,
    int* __restrict__ cursor, int* __restrict__ atok, float* __restrict__ awgt){
  int t = blockIdx.x*256 + threadIdx.x;
  if (t >= NT_TOK) return;
  #pragma unroll
  for (int k=0;k<2;k++){
    int e = topi[2*t+k];
    int pos = atomicAdd(&cursor[e], 1);
    int slot = off[e] + pos;
    atok[slot] = t;
    awgt[slot] = topw[2*t+k];
  }
}

// ---------------- GEMM1: H = gelu(X_gathered @ W1[e] + b1[e]) ----------------
// AF32: A staged directly from f32 x (no XB buffer), converted to f16 in-register.

template<bool AF32>
__global__ __launch_bounds__(256) void gemm1_kernel(
    const void* __restrict__ Xsrc, const unsigned short* __restrict__ W1T,
    const float* __restrict__ b1, const int* __restrict__ atok,
    const int* __restrict__ offs, unsigned short* __restrict__ H, int c0){
  __shared__ float Asf[AF32 ? (BM*BKK) : (BM*BKK/2)];
  __shared__ unsigned short Bs[BN*BKK];
  int nt = blockIdx.x, mt = blockIdx.y;
  int total = offs[NE];
  int m0 = c0 + mt*BM;
  if (m0 >= total) return;
  int e = 0;
  #pragma unroll
  for (int q=0;q<NE-1;q++) if (m0 >= offs[q+1]) e = q+1;
  int tid = threadIdx.x;

  const int NA = AF32 ? 8 : 4;           // 16B staging chunks per thread for A
  const float* xf = (const float*)Xsrc;
  const unsigned short* xh = (const unsigned short*)Xsrc;
  const void* ag[AF32 ? 8 : 4];
  int aofs[AF32 ? 8 : 4];
  #pragma unroll
  for (int j=0;j<NA;j++){
    int c = j*256 + tid;
    int r, sb;                            // row, byte offset within row
    if (AF32){ r = c>>4; sb = (c&15)*16; }
    else     { r = c>>3; sb = (c&7)*16; }
    int tok = atok[m0 + r];
    if (tok < 0) tok = 0;                 // pad rows: safe dummy gather
    ag[j] = AF32 ? (const void*)((const char*)(xf + (size_t)tok*DM) + sb)
                 : (const void*)((const char*)(xh + (size_t)tok*DM) + sb);
    aofs[j] = c*16;                       // byte offset in Asf
  }
  const unsigned short* bg[4];
  int bofs[4];
  #pragma unroll
  for (int j=0;j<4;j++){
    int c = j*256 + tid;
    int r = c>>3, s = c&7;
    bg[j] = W1T + ((size_t)e*DH + nt*BN + r)*DM + s*8;
    bofs[j] = c*16;
  }

  f32x4 acc[4][4];
  #pragma unroll
  for (int i=0;i<4;i++)
    #pragma unroll
    for (int j=0;j<4;j++) acc[i][j] = 0.0f;

  int lane = tid&63;
  int wm = tid>>7, wn = (tid>>6)&1;
  int arow = wm*64 + (lane&15);
  int ak0  = (lane>>4)*8;
  int brr  = (wn*64 + (lane&15))*BKK + ak0;
  const unsigned short* Ash = (const unsigned short*)Asf;

  for (int kt=0; kt<DM/BKK; ++kt){
    #pragma unroll
    for (int j=0;j<NA;j++)
      async16((const char*)ag[j] + (size_t)kt*BKK*(AF32?4:2), (char*)Asf + aofs[j]);
    #pragma unroll
    for (int j=0;j<4;j++)
      async16(bg[j] + (size_t)kt*BKK, (char*)Bs + bofs[j]);
    __syncthreads();
    #pragma unroll
    for (int kk=0; kk<BKK; kk+=32){
      f16x8 a[4], b[4];
      #pragma unroll
      for (int f=0;f<4;f++){
        if (AF32){
          f32x8 v = *(const f32x8*)&Asf[(arow + f*16)*BKK + ak0 + kk];
          a[f] = __builtin_convertvector(v, f16x8);
        } else {
          a[f] = *(const f16x8*)&Ash[(arow + f*16)*BKK + ak0 + kk];
        }
        b[f] = *(const f16x8*)&Bs[brr + f*16*BKK + kk];
      }
      #pragma unroll
      for (int i=0;i<4;i++)
        #pragma unroll
        for (int j2=0;j2<4;j2++)
          acc[i][j2] = __builtin_amdgcn_mfma_f32_16x16x32_f16(a[i], b[j2], acc[i][j2], 0,0,0);
    }
    __syncthreads();
  }
  const float* b1e = b1 + (size_t)e*DH;
  int rloc = (m0 - c0) + wm*64 + ((lane>>4)<<2);
  int nbase = nt*BN + wn*64 + (lane&15);
  #pragma unroll
  for (int i=0;i<4;i++)
    #pragma unroll
    for (int j=0;j<4;j++){
      int nn = nbase + j*16;
      float bias = b1e[nn];
      #pragma unroll
      for (int r2=0;r2<4;r2++){
        float v = acc[i][j][r2] + bias;
        float g = 0.5f*v*(1.0f + erff(v*0.70710678118654752f));
        H[(size_t)(rloc + i*16 + r2)*DH + nn] = f2h_bits(g);
      }
    }
}

// ---------------- GEMM2: out[token] += w * (H @ W2[e] + b2[e]) ----------------

__global__ __launch_bounds__(256) void gemm2_kernel(
    const unsigned short* __restrict__ H, const unsigned short* __restrict__ W2T,
    const float* __restrict__ b2, const int* __restrict__ atok,
    const float* __restrict__ awgt, const int* __restrict__ offs,
    float* __restrict__ out, int c0){
  __shared__ unsigned short As[BM*BKK];
  __shared__ unsigned short Bs[BN*BKK];
  int nt = blockIdx.x, mt = blockIdx.y;
  int total = offs[NE];
  int m0 = c0 + mt*BM;
  if (m0 >= total) return;
  int e = 0;
  #pragma unroll
  for (int q=0;q<NE-1;q++) if (m0 >= offs[q+1]) e = q+1;
  int tid = threadIdx.x;
  const unsigned short* ag[4];
  const unsigned short* bg[4];
  int lofs[4];
  #pragma unroll
  for (int j=0;j<4;j++){
    int c = j*256 + tid;
    int r = c>>3, s = c&7;
    ag[j] = H + (size_t)(m0 - c0 + r)*DH + s*8;
    bg[j] = W2T + ((size_t)e*DM + nt*BN + r)*DH + s*8;
    lofs[j] = c*8;
  }
  f32x4 acc[4][4];
  #pragma unroll
  for (int i=0;i<4;i++)
    #pragma unroll
    for (int j=0;j<4;j++) acc[i][j] = 0.0f;
  int lane = tid&63;
  int wm = tid>>7, wn = (tid>>6)&1;
  int ar  = (wm*64 + (lane&15))*BKK + ((lane>>4)*8);
  int brr = (wn*64 + (lane&15))*BKK + ((lane>>4)*8);
  for (int kt=0; kt<DH/BKK; ++kt){
    #pragma unroll
    for (int j=0;j<4;j++){
      async16(ag[j] + (size_t)kt*BKK, &As[lofs[j]]);
      async16(bg[j] + (size_t)kt*BKK, &Bs[lofs[j]]);
    }
    __syncthreads();
    #pragma unroll
    for (int kk=0; kk<BKK; kk+=32){
      f16x8 a[4], b[4];
      #pragma unroll
      for (int f=0;f<4;f++){
        a[f] = *(const f16x8*)&As[ar  + f*16*BKK + kk];
        b[f] = *(const f16x8*)&Bs[brr + f*16*BKK + kk];
      }
      #pragma unroll
      for (int i=0;i<4;i++)
        #pragma unroll
        for (int j2=0;j2<4;j2++)
          acc[i][j2] = __builtin_amdgcn_mfma_f32_16x16x32_f16(a[i], b[j2], acc[i][j2], 0,0,0);
    }
    __syncthreads();
  }
  const float* b2e = b2 + (size_t)e*DM;
  int rbase = m0 + wm*64 + ((lane>>4)<<2);
  int nbase = nt*BN + wn*64 + (lane&15);
  #pragma unroll
  for (int i=0;i<4;i++){
    #pragma unroll
    for (int r2=0;r2<4;r2++){
      int slot = rbase + i*16 + r2;
      int tok = atok[slot];
      float wgt = awgt[slot];
      if (tok >= 0){
        #pragma unroll
        for (int j=0;j<4;j++){
          int nn = nbase + j*16;
          float v = acc[i][j][r2] + b2e[nn];
          atomicAdd(&out[(size_t)tok*DM + nn], wgt*v);
        }
      }
    }
  }
}

__global__ void fill_kernel(float* p, float v, size_t n){
  size_t i = (size_t)blockIdx.x*256 + threadIdx.x;
  if (i < n) p[i] = v;
}

// ---------------- launch ----------------

extern "C" void kernel_launch(void* const* d_in, const int* in_sizes, int n_in,
                              void* d_out, int out_size, void* d_ws, size_t ws_size,
                              hipStream_t stream){
  const float* x  = (const float*)d_in[0];
  const float* Wr = (const float*)d_in[1];
  const float* br = (const float*)d_in[2];
  const float* W1 = (const float*)d_in[3];
  const float* b1 = (const float*)d_in[4];
  const float* W2 = (const float*)d_in[5];
  const float* b2 = (const float*)d_in[6];
  float* out = (float*)d_out;

  char* ws = (char*)d_ws;
  size_t o = 0;
  auto take = [&](size_t bytes)->void*{
    void* p = ws + o; o += (bytes + 255) & ~(size_t)255; return p;
  };
  // mandatory
  unsigned short* W1T = (unsigned short*)take((size_t)NE*DM*DH*2);
  unsigned short* W2T = (unsigned short*)take((size_t)NE*DM*DH*2);
  int*   TOPI = (int*)take((size_t)NT_TOK*2*4);
  float* TOPW = (float*)take((size_t)NT_TOK*2*4);
  int*   ATOK = (int*)take((size_t)CAP*4);
  float* AWGT = (float*)take((size_t)CAP*4);
  int*   CNT  = (int*)take(256);     // counts[8] | cursor[8] | off[9]
  int* CUR = CNT + 8;
  int* OFF = CNT + 16;

  if (o + (size_t)BM*DH*2 > ws_size){
    // cannot even fit mandatory + one minimal H chunk
    fill_kernel<<<(unsigned)((out_size+255)/256), 256, 0, stream>>>(out, 4321.5f, (size_t)out_size);
    return;
  }

  // optional XB (f16 x), if it leaves >= 2048 rows of H chunk
  unsigned short* XB = nullptr;
  bool use_xb = false;
  {
    size_t xb_bytes = (size_t)NT_TOK*DM*2 + 256;
    size_t need_h  = (size_t)2048*DH*2;
    if (o + xb_bytes + need_h <= ws_size){
      use_xb = true;
      XB = (unsigned short*)take((size_t)NT_TOK*DM*2);
    }
  }
  // H chunk: everything that remains
  size_t rem = ws_size - o;
  size_t cr = (rem / ((size_t)DH*2)) / BM * BM;
  if (cr > (size_t)CAP) cr = CAP;
  if (cr < BM){
    fill_kernel<<<(unsigned)((out_size+255)/256), 256, 0, stream>>>(out, 4321.5f, (size_t)out_size);
    return;
  }
  unsigned short* Hb = (unsigned short*)take(cr*(size_t)DH*2);
  int CR = (int)cr;
  int nch = (CAP + CR - 1)/CR;

  hipMemsetAsync(CNT, 0, 64, stream);
  hipMemsetAsync(ATOK, 0xFF, (size_t)CAP*4, stream);            // token = -1
  hipMemsetAsync(out, 0, (size_t)out_size*sizeof(float), stream);

  if (use_xb)
    cvt_f16_kernel<<<(NT_TOK*DM/8 + 255)/256, 256, 0, stream>>>(x, XB, NT_TOK*DM/8);
  transpose_f16_kernel<<<dim3(DH/32, DM/32, NE), dim3(32,8), 0, stream>>>(W1, W1T, DM, DH);
  transpose_f16_kernel<<<dim3(DM/32, DH/32, NE), dim3(32,8), 0, stream>>>(W2, W2T, DH, DM);
  router_kernel<<<NT_TOK/4, 256, 0, stream>>>(x, Wr, br, TOPI, TOPW, CNT);
  offsets_kernel<<<1, 1, 0, stream>>>(CNT, OFF);
  scatter_kernel<<<NT_TOK/256, 256, 0, stream>>>(TOPI, TOPW, OFF, CUR, ATOK, AWGT);

  for (int c = 0; c < nch; ++c){
    int c0 = c*CR;
    if (use_xb)
      gemm1_kernel<false><<<dim3(DH/BN, CR/BM), 256, 0, stream>>>(
        (const void*)XB, W1T, b1, ATOK, OFF, Hb, c0);
    else
      gemm1_kernel<true><<<dim3(DH/BN, CR/BM), 256, 0, stream>>>(
        (const void*)x, W1T, b1, ATOK, OFF, Hb, c0);
    gemm2_kernel<<<dim3(DM/BN, CR/BM), 256, 0, stream>>>(
        Hb, W2T, b2, ATOK, AWGT, OFF, out, c0);
  }
}